// Round 6
// baseline (287.857 us; speedup 1.0000x reference)
//
#include <hip/hip_runtime.h>
#include <stdint.h>

typedef unsigned short u16;
typedef unsigned int   u32;

#define NTOK   32768      // B*P
#define GD     768
#define GH     256
#define GH2    128
#define GE     64

typedef __bf16 bf16x8 __attribute__((ext_vector_type(8)));
typedef float  f32x4  __attribute__((ext_vector_type(4)));
union Frag { uint4 u; bf16x8 b; };

__device__ __forceinline__ float bf2f(u16 h) {
  union { u32 u; float f; } v; v.u = ((u32)h) << 16; return v.f;
}
__device__ __forceinline__ u16 f2bf(float f) {
  union { float f; u32 u; } v; v.f = f;
  u32 r = (v.u + 0x7fffu + ((v.u >> 16) & 1u)) >> 16;
  return (u16)r;
}

__device__ __forceinline__ void async16(void* lds, const void* g) {
  __builtin_amdgcn_global_load_lds(
      (const __attribute__((address_space(1))) void*)g,
      (__attribute__((address_space(3))) void*)lds, 16, 0, 0);
}

__device__ __forceinline__ int getProp(const int* p32, int t, int is64) {
  return is64 ? p32[2 * t] : p32[t];
}

// ---------------- workspace layout (bytes) ----------------
static const size_t OFF_W1T  = 0;            // bf16 64*256*768*2 = 25165824
static const size_t OFF_W2T  = 25165824;     // bf16 64*128*256*2 = 4194304
static const size_t OFF_TOK  = 29360128;     // int NTOK*4
static const size_t OFF_META = 29491200;     // ints
// meta ints: counts2d[8192]@0 ([e][b] transposed), offsets[65]@8192,
//   tileHead[1024]@8320, tileRow[1024]@9344, nTiles@10368, flag@10369,
//   cursors_p[1024]@10432

// ---------------- K0: setup + W1 transpose + W2 transpose (branched) ----------
__global__ void mega_prep(const int* __restrict__ prop, const float* __restrict__ mask,
                          const float* __restrict__ W1, const float* __restrict__ W2,
                          u32* __restrict__ outz, u16* __restrict__ w1t,
                          u16* __restrict__ w2t, int* __restrict__ counts2d,
                          int* __restrict__ cursors_p, int* __restrict__ flagp) {
  __shared__ union SM {
    struct { int h[GE]; int vOr; } st;
    u16 w1[64][260];          // 33.3 KB
    u16 t32[32][33];
  } sm;
  const int b = blockIdx.x;                 // grid 2944
  const int tid = threadIdx.x;

  if (b < 128) {
    // ---- setup: zero d_out/cursors, detect prop dtype, per-block histogram ----
    outz[b * 512 + tid] = 0u;
    outz[b * 512 + 256 + tid] = 0u;
    if (b < 4) cursors_p[b * 256 + tid] = 0;
    if (tid < GE) sm.st.h[tid] = 0;
    if (tid == 0) sm.st.vOr = 0;
    __syncthreads();
    int v = prop[2 * tid + 1] | prop[2 * (tid + 256) + 1];
    if (v) atomicOr(&sm.st.vOr, 1);
    __syncthreads();
    const int is64 = (sm.st.vOr == 0) ? 1 : 0;
    if (b == 0 && tid == 0) *flagp = is64;
    const int t = b * 256 + tid;
    if (mask[t] > 0.f) atomicAdd(&sm.st.h[getProp(prop, t, is64)], 1);
    __syncthreads();
    if (tid < GE) counts2d[tid * 128 + b] = sm.st.h[tid];   // [e][b] for int4 scan
  } else if (b < 896) {
    // ---- W1 fp32 [64][768][256] -> bf16 [64][256][768] ----
    const int bid = b - 128;                 // 768 blocks
    const int e  = bid / 12, r = bid % 12;
    const int d0 = (r / 4) * 256, h0 = (r % 4) * 64;
    const size_t inMat = (size_t)e * GD * GH;
    const size_t outMat = (size_t)e * GH * GD;
    const int h_l = (tid & 15) * 4, d_l = tid >> 4;
#pragma unroll
    for (int dd = 0; dd < 16; ++dd) {
      const int d = d_l + dd * 16;
      float4 v = *(const float4*)(W1 + inMat + (size_t)(d0 + d) * GH + h0 + h_l);
      sm.w1[h_l + 0][d] = f2bf(v.x);
      sm.w1[h_l + 1][d] = f2bf(v.y);
      sm.w1[h_l + 2][d] = f2bf(v.z);
      sm.w1[h_l + 3][d] = f2bf(v.w);
    }
    __syncthreads();
    const int wv = tid >> 6, ln = tid & 63;
#pragma unroll
    for (int hh = 0; hh < 16; ++hh) {
      const int h = wv * 16 + hh;
      *(uint2*)(w1t + outMat + (size_t)(h0 + h) * GD + d0 + ln * 4) =
          *(const uint2*)&sm.w1[h][ln * 4];
    }
  } else {
    // ---- W2 fp32 [64][256][128] -> bf16 [64][128][256] (32x32 tiles) ----
    const int bid = b - 896;                 // 2048 blocks
    const int R = GH, C = GH2, tilesC = 4, tilesPerMat = 32;
    const int e  = bid / tilesPerMat;
    const int t  = bid % tilesPerMat;
    const int tr = t / tilesC, tc = t % tilesC;
    const size_t mat = (size_t)e * R * C;
    const int tx = tid & 31, ty = tid >> 5;
    const int r0 = tr * 32, c0 = tc * 32;
#pragma unroll
    for (int i = 0; i < 32; i += 8)
      sm.t32[ty + i][tx] = f2bf(W2[mat + (size_t)(r0 + ty + i) * C + c0 + tx]);
    __syncthreads();
#pragma unroll
    for (int i = 0; i < 32; i += 8)
      w2t[mat + (size_t)(c0 + ty + i) * R + r0 + tx] = sm.t32[tx][ty + i];
  }
}

// ---------------- K1: reduce counts + scan + tile table (1 wave) --------------
__global__ void scan_kernel(const int* __restrict__ counts2d, int* __restrict__ offsets,
                            int* __restrict__ tileHead, int* __restrict__ tileRow,
                            int* __restrict__ nTilesPtr) {
  const int e = threadIdx.x;  // 0..63
  int c = 0;
  const int4* p = (const int4*)(counts2d + e * 128);
#pragma unroll
  for (int i = 0; i < 32; ++i) { int4 v = p[i]; c += v.x + v.y + v.z + v.w; }
  int inc = c;
#pragma unroll
  for (int d = 1; d < 64; d <<= 1) { int n = __shfl_up(inc, d); if (e >= d) inc += n; }
  const int off = inc - c;
  offsets[e] = off;
  if (e == 63) offsets[64] = inc;
  int ntile = (c + 63) >> 6;
  int inct = ntile;
#pragma unroll
  for (int d = 1; d < 64; d <<= 1) { int n = __shfl_up(inct, d); if (e >= d) inct += n; }
  const int tb = inct - ntile;
  for (int j = 0; j < ntile; ++j) { tileHead[tb + j] = e; tileRow[tb + j] = off + j * 64; }
  if (e == 63) *nTilesPtr = inct;
}

// ---------------- K2: two-phase block scatter ---------------------------------
__global__ void scatter_kernel(const int* __restrict__ prop, const float* __restrict__ mask,
                               const int* __restrict__ offsets, int* __restrict__ cursors_p,
                               int* __restrict__ tokenIds, const int* __restrict__ flag) {
  __shared__ int h[GE];
  __shared__ int basebin[GE];
  const int tid = threadIdx.x;
  const int t = blockIdx.x * 256 + tid;  // grid 128
  if (tid < GE) h[tid] = 0;
  __syncthreads();
  int p = -1, rank = 0;
  if (mask[t] > 0.f) {
    p = getProp(prop, t, *flag);
    rank = atomicAdd(&h[p], 1);
  }
  __syncthreads();
  if (tid < GE && h[tid] > 0) basebin[tid] = atomicAdd(&cursors_p[tid * 16], h[tid]);
  __syncthreads();
  if (p >= 0) tokenIds[offsets[p] + basebin[p] + rank] = t;
}

// ---------------- K3: LN-fused grouped adapter GEMM (63.75 KB LDS) ------------
__global__ __launch_bounds__(256, 2) void adapter_gemm(
    const float* __restrict__ hs, const float* __restrict__ lng, const float* __restrict__ lnb,
    const u16* __restrict__ w1t, const u16* __restrict__ w2t,
    const float* __restrict__ b1, const float* __restrict__ b2,
    const float* __restrict__ w3, const float* __restrict__ b3,
    const float* __restrict__ base, const float* __restrict__ mask,
    const int* __restrict__ tokenIds, const int* __restrict__ offsets,
    const int* __restrict__ tileHead, const int* __restrict__ tileRow,
    const int* __restrict__ nTilesPtr, float* __restrict__ outp) {
  __shared__ union LU {
    struct {                    // live during GEMM1 only
      u16 A[2][2048];           //  8 KB  [par][kgrp4][row64][8]
      u16 B[2][8192];           // 32 KB  [par][kgrp4][n256][8]
      u16 G[768];               // gamma bf16
      u16 Bt[768];              // beta  bf16
      float mu[64];
      float rstd[64];
    } s;                        // 44544 B
    u16 h[17408];               // h1 (stride 264) / h2 (stride 130), 34.8 KB
  } uni;
  __shared__ u16 sB2[2][4096];  // GEMM2 B staging, 16 KB
  __shared__ float sBias1[256];
  __shared__ float sBias2[128];
  __shared__ float sW3[2][128];
  __shared__ float sB3[2];
  __shared__ int   sTok[64];

  const int tid  = threadIdx.x;
  const int wv   = tid >> 6;
  const int ln   = tid & 63;
  const int l15  = tid & 15;
  const int quad = (tid & 63) >> 4;
  const f32x4 vzero = {0.f, 0.f, 0.f, 0.f};
  const int nt = *nTilesPtr;

  for (int tile = blockIdx.x; tile < nt; tile += gridDim.x) {
    __syncthreads();  // protect LDS/meta reuse across tiles (prev GEMM3 reads)
    const int e  = tileHead[tile];
    const int rs = tileRow[tile];
    const int nRows = min(64, offsets[e + 1] - rs);

    if (tid < 64) sTok[tid] = tokenIds[rs + min(tid, nRows - 1)];
    sBias1[tid] = b1[e * GH + tid];
    if (tid < 128) sBias2[tid] = b2[e * GH2 + tid];
    { const int k = tid >> 1, o = tid & 1; sW3[o][k] = w3[e * GH2 * 2 + k * 2 + o]; }
    if (tid < 2) sB3[tid] = b3[e * 2 + tid];
    // gamma/beta -> bf16 LDS (union GEMM1 branch)
#pragma unroll
    for (int i = 0; i < 3; ++i) {
      const int idx = i * 256 + tid;
      uni.s.G[idx]  = f2bf(lng[e * GD + idx]);
      uni.s.Bt[idx] = f2bf(lnb[e * GD + idx]);
    }
    __syncthreads();   // sTok visible for stats

    // ---- LN stats: 4 lanes per row, 48 float4 each ----
    {
      const int srow = tid >> 2, sj = tid & 3;
      const float* xr = hs + (size_t)sTok[srow] * GD;
      float s = 0.f, sq = 0.f;
#pragma unroll
      for (int i = 0; i < 48; ++i) {
        float4 u = *(const float4*)(xr + i * 16 + sj * 4);
        s  += u.x + u.y + u.z + u.w;
        sq += u.x * u.x + u.y * u.y + u.z * u.z + u.w * u.w;
      }
      s += __shfl_xor(s, 1);  s += __shfl_xor(s, 2);
      sq += __shfl_xor(sq, 1); sq += __shfl_xor(sq, 2);
      if (sj == 0) {
        const float m = s * (1.f / 768.f);
        uni.s.mu[srow]   = m;
        uni.s.rstd[srow] = rsqrtf(sq * (1.f / 768.f) - m * m + 1e-5f);
      }
    }
    __syncthreads();   // stats + gamma/beta visible

    const float* xrow = hs + (size_t)sTok[ln] * GD;
    const u16* w1e = w1t + (size_t)e * GH * GD;
    const u16* w2e = w2t + (size_t)e * GH2 * GH;
    const float lmu = uni.s.mu[ln];
    const float lrs = uni.s.rstd[ln];

    // ---- GEMM1: LN(hs)[64x768] @ W1t -> h1[64x256]; 24 k-steps ----
    f32x4 acc1[4][4];
#pragma unroll
    for (int f = 0; f < 4; ++f)
#pragma unroll
      for (int g = 0; g < 4; ++g) acc1[f][g] = vzero;

    // preload hs frag kt=0 (ordered BEFORE async16 so use waits at vmcnt(4))
    float4 pa = *(const float4*)(xrow + wv * 8);
    float4 pb = *(const float4*)(xrow + wv * 8 + 4);
#pragma unroll
    for (int j = 0; j < 4; ++j)
      async16(uni.s.B[0] + wv * 2048 + j * 512,
              w1e + (size_t)(j * 64 + ln) * GD + wv * 8);

    for (int kt = 0; kt < 24; ++kt) {
      const int par = kt & 1;
      // normalize pending hs frag -> bf16 -> staging A[par]
      {
        const int kb = kt * 32 + wv * 8;
        const uint4 gv = *(const uint4*)&uni.s.G[kb];
        const uint4 bv = *(const uint4*)&uni.s.Bt[kb];
        const float xn0 = (pa.x - lmu) * lrs * bf2f((u16)(gv.x & 0xffff)) + bf2f((u16)(bv.x & 0xffff));
        const float xn1 = (pa.y - lmu) * lrs * bf2f((u16)(gv.x >> 16))    + bf2f((u16)(bv.x >> 16));
        const float xn2 = (pa.z - lmu) * lrs * bf2f((u16)(gv.y & 0xffff)) + bf2f((u16)(bv.y & 0xffff));
        const float xn3 = (pa.w - lmu) * lrs * bf2f((u16)(gv.y >> 16))    + bf2f((u16)(bv.y >> 16));
        const float xn4 = (pb.x - lmu) * lrs * bf2f((u16)(gv.z & 0xffff)) + bf2f((u16)(bv.z & 0xffff));
        const float xn5 = (pb.y - lmu) * lrs * bf2f((u16)(gv.z >> 16))    + bf2f((u16)(bv.z >> 16));
        const float xn6 = (pb.z - lmu) * lrs * bf2f((u16)(gv.w & 0xffff)) + bf2f((u16)(bv.w & 0xffff));
        const float xn7 = (pb.w - lmu) * lrs * bf2f((u16)(gv.w >> 16))    + bf2f((u16)(bv.w >> 16));
        uint4 pk;
        pk.x = (u32)f2bf(xn0) | ((u32)f2bf(xn1) << 16);
        pk.y = (u32)f2bf(xn2) | ((u32)f2bf(xn3) << 16);
        pk.z = (u32)f2bf(xn4) | ((u32)f2bf(xn5) << 16);
        pk.w = (u32)f2bf(xn6) | ((u32)f2bf(xn7) << 16);
        *(uint4*)&uni.s.A[par][wv * 512 + ln * 8] = pk;
      }
      __syncthreads();   // drains B[par] async16 (issued one iter ago) + A ds_writes
      if (kt + 1 < 24) {
        const int k0 = (kt + 1) * 32;
        pa = *(const float4*)(xrow + k0 + wv * 8);     // regs for next iter
        pb = *(const float4*)(xrow + k0 + wv * 8 + 4);
#pragma unroll
        for (int j = 0; j < 4; ++j)
          async16(uni.s.B[(kt + 1) & 1] + wv * 2048 + j * 512,
                  w1e + (size_t)(j * 64 + ln) * GD + k0 + wv * 8);
      }
      Frag fa[4], fb[4];
#pragma unroll
      for (int f = 0; f < 4; ++f)
        fa[f].u = *(const uint4*)&uni.s.A[par][quad * 512 + (f * 16 + l15) * 8];
#pragma unroll
      for (int g = 0; g < 4; ++g)
        fb[g].u = *(const uint4*)&uni.s.B[par][quad * 2048 + (wv * 64 + g * 16 + l15) * 8];
#pragma unroll
      for (int f = 0; f < 4; ++f)
#pragma unroll
        for (int g = 0; g < 4; ++g)
          acc1[f][g] = __builtin_amdgcn_mfma_f32_16x16x32_bf16(fa[f].b, fb[g].b, acc1[f][g], 0, 0, 0);
    }
    __syncthreads();   // staging region fully read -> uni.h writable

    // prefetch GEMM2 B kt=0 (separate region; overlaps epilogue VALU)
#pragma unroll
    for (int j = 0; j < 2; ++j)
      async16(sB2[0] + wv * 1024 + j * 512,
              w2e + (size_t)(j * 64 + ln) * GH + wv * 8);

    // epilogue 1: +b1, relu -> uni.h (stride 264)
#pragma unroll
    for (int f = 0; f < 4; ++f)
#pragma unroll
      for (int g = 0; g < 4; ++g) {
        const int col = wv * 64 + g * 16 + l15;
        const float bias = sBias1[col];
#pragma unroll
        for (int r = 0; r < 4; ++r) {
          const int row = f * 16 + quad * 4 + r;
          uni.h[row * 264 + col] = f2bf(fmaxf(acc1[f][g][r] + bias, 0.f));
        }
      }

    // ---- GEMM2: h1[64x256] @ W2t -> 64x128; 8 k-steps ----
    f32x4 acc2[4][2];
#pragma unroll
    for (int f = 0; f < 4; ++f)
#pragma unroll
      for (int g = 0; g < 2; ++g) acc2[f][g] = vzero;

    for (int kt = 0; kt < 8; ++kt) {
      __syncthreads();   // drains kt's sB2 loads; makes h1 visible (kt=0)
      if (kt + 1 < 8) {
        const int k0 = (kt + 1) * 32;
        const int par = (kt + 1) & 1;
#pragma unroll
        for (int j = 0; j < 2; ++j)
          async16(sB2[par] + wv * 1024 + j * 512,
                  w2e + (size_t)(j * 64 + ln) * GH + k0 + wv * 8);
      }
      const int par = kt & 1;
      Frag fa2[4], fb2[2];
#pragma unroll
      for (int f = 0; f < 4; ++f)
        fa2[f].u = *(const uint4*)&uni.h[(f * 16 + l15) * 264 + kt * 32 + quad * 8];
#pragma unroll
      for (int g = 0; g < 2; ++g)
        fb2[g].u = *(const uint4*)&sB2[par][quad * 1024 + (wv * 32 + g * 16 + l15) * 8];
#pragma unroll
      for (int f = 0; f < 4; ++f)
#pragma unroll
        for (int g = 0; g < 2; ++g)
          acc2[f][g] = __builtin_amdgcn_mfma_f32_16x16x32_bf16(fa2[f].b, fb2[g].b, acc2[f][g], 0, 0, 0);
    }
    __syncthreads();   // h1 reads done -> overwrite with h2

    // epilogue 2: +b2, relu -> uni.h as h2 (stride 130)
#pragma unroll
    for (int f = 0; f < 4; ++f)
#pragma unroll
      for (int g = 0; g < 2; ++g) {
        const int col = wv * 32 + g * 16 + l15;
        const float bias = sBias2[col];
#pragma unroll
        for (int r = 0; r < 4; ++r) {
          const int row = f * 16 + quad * 4 + r;
          uni.h[row * 130 + col] = f2bf(fmaxf(acc2[f][g][r] + bias, 0.f));
        }
      }
    __syncthreads();

    // ---------- GEMM3 + residual + mask + scatter-store (fp32) ----------
    const int m = tid >> 1, o = tid & 1;
    if (m < nRows) {
      float a = sB3[o];
      const u16* h2row = &uni.h[m * 130];
#pragma unroll 16
      for (int k = 0; k < 128; ++k) a += bf2f(h2row[k]) * sW3[o][k];
      const int t = sTok[m];
      const float mk = mask[t];
      const float bs = base[t * 2 + o];
      outp[t * 2 + o] = (0.7f * a + 0.3f * bs) * mk;
    }
  }
}

extern "C" void kernel_launch(void* const* d_in, const int* in_sizes, int n_in,
                              void* d_out, int out_size, void* d_ws, size_t ws_size,
                              hipStream_t stream) {
  const float* hs   = (const float*)d_in[0];
  const float* base = (const float*)d_in[1];
  const int*   prop = (const int*)d_in[2];
  const float* mask = (const float*)d_in[3];
  const float* lng  = (const float*)d_in[4];
  const float* lnb  = (const float*)d_in[5];
  const float* W1   = (const float*)d_in[6];
  const float* b1   = (const float*)d_in[7];
  const float* W2   = (const float*)d_in[8];
  const float* b2   = (const float*)d_in[9];
  const float* W3   = (const float*)d_in[10];
  const float* b3   = (const float*)d_in[11];

  char* ws = (char*)d_ws;
  u16* w1t  = (u16*)(ws + OFF_W1T);
  u16* w2t  = (u16*)(ws + OFF_W2T);
  int* tok  = (int*)(ws + OFF_TOK);
  int* meta = (int*)(ws + OFF_META);
  int* counts2d  = meta;           // 8192 ints, [e][b]
  int* offsets   = meta + 8192;    // 65 ints
  int* tileHead  = meta + 8320;    // 1024 ints
  int* tileRow   = meta + 9344;    // 1024 ints
  int* nTiles    = meta + 10368;
  int* propFlag  = meta + 10369;
  int* cursors_p = meta + 10432;   // 1024 ints (64 bins, 64B-padded)

  mega_prep<<<2944, 256, 0, stream>>>(prop, mask, W1, W2, (u32*)d_out,
                                      w1t, w2t, counts2d, cursors_p, propFlag);
  scan_kernel<<<1, 64, 0, stream>>>(counts2d, offsets, tileHead, tileRow, nTiles);
  scatter_kernel<<<NTOK / 256, 256, 0, stream>>>(prop, mask, offsets, cursors_p, tok, propFlag);
  adapter_gemm<<<640, 256, 0, stream>>>(hs, lng, lnb, w1t, w2t, b1, b2, W3, b3,
                                        base, mask, tok, offsets, tileHead, tileRow,
                                        nTiles, (float*)d_out);
}